// Round 6
// baseline (98.068 us; speedup 1.0000x reference)
//
#include <hip/hip_runtime.h>
#include <stdint.h>

// SelfOrganizingMap: B=128, D=256, H=W=64.
// Output depends ONLY on initial-weight BMU coords + Gaussian field sums:
//   mem[h,w] = mem0[h,w] + sum_b 0.5*exp(-norm([h,w]-bmu_b)^2 / 8)
//   out = (mem > thr) ? 1 : 0
// The weight updates in the reference scan are dead w.r.t. the output, and
// BMUs are computed from the INITIAL weights -> fully parallel problem.

#define B_   128
#define D_   256
#define HW_  4096       // 64*64 units
#define BG   8          // batches per block (weight-reuse factor)
#define NBG  (B_/BG)    // 16
#define USL  16         // unit slices
#define PARTS 64        // partial minima per b: USL * 4 waves

// Kernel A: per-(b, unit) distance + per-wave argmin partials.
// Lane owns one unit; streams its 1KB weight row; x broadcast from LDS.
__global__ __launch_bounds__(256) void som_bmu(
    const float* __restrict__ x, const float* __restrict__ w,
    unsigned long long* __restrict__ part) {
  __shared__ float xs[BG][D_];
  const int bg  = blockIdx.x;   // 0..15
  const int us  = blockIdx.y;   // 0..15
  const int tid = threadIdx.x;

  // stage x tile (8 batches x 256 dims = 2048 floats = 8KB) into LDS
  const float4* xg  = (const float4*)(x + bg * BG * D_);
  float4*       xsv = (float4*)(&xs[0][0]);
  xsv[tid]       = xg[tid];
  xsv[tid + 256] = xg[tid + 256];
  __syncthreads();

  const int wave = tid >> 6, lane = tid & 63;
  const int u = us * (HW_ / USL) + wave * 64 + lane;   // this lane's unit
  const float4* wrow = (const float4*)(w + (size_t)u * D_);

  float acc[BG];
#pragma unroll
  for (int b = 0; b < BG; ++b) acc[b] = 0.f;

#pragma unroll 4
  for (int d4 = 0; d4 < D_ / 4; ++d4) {
    float4 wv = wrow[d4];                       // per-lane sequential stream
#pragma unroll
    for (int b = 0; b < BG; ++b) {
      float4 xv = ((const float4*)xs[b])[d4];   // same addr all lanes: broadcast
      float t0 = xv.x - wv.x, t1 = xv.y - wv.y;
      float t2 = xv.z - wv.z, t3 = xv.w - wv.w;
      acc[b] += t0 * t0 + t1 * t1 + t2 * t2 + t3 * t3;
    }
  }

  // Reference argmins over NORMS (sqrt of the sum). sqrt is monotone, but two
  // distinct squared sums can round to the same norm -> apply sqrtf BEFORE
  // packing so idx tie-break matches jnp.argmin's first-index rule exactly.
  // Packed (norm_bits<<32)|idx: unsigned min == (min norm, then min idx).
#pragma unroll
  for (int b = 0; b < BG; ++b) {
    unsigned long long p =
        ((unsigned long long)__float_as_uint(sqrtf(acc[b])) << 32) | (unsigned)u;
    for (int off = 32; off > 0; off >>= 1) {
      unsigned long long q = __shfl_xor(p, off, 64);
      p = q < p ? q : p;
    }
    if (lane == 0) part[(bg * BG + b) * PARTS + us * 4 + wave] = p;
  }
}

// Kernel B: finish argmin per b (all 16 blocks redo the tiny 64-way reduce —
// 8KB L2-hot, cheaper than another kernel), then Gaussian field + threshold.
__global__ __launch_bounds__(256) void som_out(
    const unsigned long long* __restrict__ part,
    const float* __restrict__ thr, const float* __restrict__ mem0,
    float* __restrict__ out) {
  __shared__ float bys[B_], bxs[B_];
  const int tid = threadIdx.x;
  if (tid < B_) {
    const unsigned long long* p = part + (size_t)tid * PARTS;
    unsigned long long m = p[0];
#pragma unroll
    for (int i = 1; i < PARTS; ++i) {
      unsigned long long q = p[i];
      m = q < m ? q : m;
    }
    unsigned idx = (unsigned)(m & 0xFFFFFFFFu);
    bys[tid] = (float)(idx >> 6);   // bmu_y = idx // W
    bxs[tid] = (float)(idx & 63);   // bmu_x = idx % W
  }
  __syncthreads();

  const int g  = blockIdx.x * 256 + tid;
  const float fy = (float)(g >> 6), fx = (float)(g & 63);

  // Match the reference scan's op sequence exactly:
  //   cd  = sqrt(dy^2 + dx^2)          (norm -> f32 rounding)
  //   nbh = exp(-(cd*cd) * 0.125)      (squared AGAIN, as in reference)
  //   mem = mem + nbh*0.5              (sequential b=0..127, from mem0)
  float mem = mem0[g];
  for (int b = 0; b < B_; ++b) {
    float dy = fy - bys[b], dx = fx - bxs[b];
    float cd = sqrtf(dy * dy + dx * dx);
    float nbh = expf(-(cd * cd) * 0.125f);  // RADIUS=2 -> 1/(2*R^2)=0.125
    mem += 0.5f * nbh;
  }
  out[g] = (mem > thr[g]) ? 1.0f : 0.0f;
}

extern "C" void kernel_launch(void* const* d_in, const int* in_sizes, int n_in,
                              void* d_out, int out_size, void* d_ws, size_t ws_size,
                              hipStream_t stream) {
  const float* x    = (const float*)d_in[0];   // [128, 256]
  const float* w    = (const float*)d_in[1];   // [64, 64, 256]
  const float* thr  = (const float*)d_in[2];   // [64, 64]
  const float* mem0 = (const float*)d_in[3];   // [64, 64]
  float* out = (float*)d_out;                  // [64, 64]
  unsigned long long* part = (unsigned long long*)d_ws;  // 128*64*8B = 64 KB

  som_bmu<<<dim3(NBG, USL), 256, 0, stream>>>(x, w, part);
  som_out<<<HW_ / 256, 256, 0, stream>>>(part, thr, mem0, out);
}

// Round 8
// 92.896 us; speedup vs baseline: 1.0557x; 1.0557x over previous
//
#include <hip/hip_runtime.h>
#include <stdint.h>

// SelfOrganizingMap: B=128, D=256, H=W=64.
// Output depends ONLY on initial-weight BMU coords + Gaussian field sums:
//   mem[h,w] = mem0[h,w] + sum_b 0.5*exp(-norm([h,w]-bmu_b)^2 / 8)
//   out = (mem > thr) ? 1 : 0
// The weight updates in the reference scan are dead w.r.t. the output.
//
// R6: BG 8->4 (512 blocks, 2 waves/SIMD instead of 1) for latency hiding on
// the LDS->VALU chains + cache-cold weight loads (the harness's 256 MiB 0xAA
// poison flushes L2/L3 every replay). Per-(b,u) FP order unchanged.

#define B_   128
#define D_   256
#define HW_  4096       // 64*64 units
#define BG   4          // batches per block (weight-reuse factor)
#define NBG  (B_/BG)    // 32
#define USL  16         // unit slices (256 units per block)
#define PARTS 64        // partial minima per b: USL * 4 waves

// Kernel A: per-(b, unit) distance + per-wave argmin partials.
// Lane owns one unit; streams its 1KB weight row; x broadcast from LDS.
__global__ __launch_bounds__(256) void som_bmu(
    const float* __restrict__ x, const float* __restrict__ w,
    unsigned long long* __restrict__ part) {
  __shared__ float xs[BG][D_];
  const int bg  = blockIdx.x;   // 0..31
  const int us  = blockIdx.y;   // 0..15
  const int tid = threadIdx.x;

  // stage x tile (4 batches x 256 dims = 1024 floats = 4KB) into LDS
  const float4* xg  = (const float4*)(x + bg * BG * D_);
  float4*       xsv = (float4*)(&xs[0][0]);
  xsv[tid] = xg[tid];
  __syncthreads();

  const int wave = tid >> 6, lane = tid & 63;
  const int u = us * (HW_ / USL) + wave * 64 + lane;   // this lane's unit
  const float4* wrow = (const float4*)(w + (size_t)u * D_);

  float acc[BG];
#pragma unroll
  for (int b = 0; b < BG; ++b) acc[b] = 0.f;

#pragma unroll 4
  for (int d4 = 0; d4 < D_ / 4; ++d4) {
    float4 wv = wrow[d4];                       // per-lane sequential stream
#pragma unroll
    for (int b = 0; b < BG; ++b) {
      float4 xv = ((const float4*)xs[b])[d4];   // same addr all lanes: broadcast
      float t0 = xv.x - wv.x, t1 = xv.y - wv.y;
      float t2 = xv.z - wv.z, t3 = xv.w - wv.w;
      acc[b] += t0 * t0 + t1 * t1 + t2 * t2 + t3 * t3;
    }
  }

  // Reference argmins over NORMS (sqrt of the sum). Apply sqrtf BEFORE
  // packing so idx tie-break matches jnp.argmin's first-index rule exactly.
  // Packed (norm_bits<<32)|idx: unsigned min == (min norm, then min idx).
#pragma unroll
  for (int b = 0; b < BG; ++b) {
    unsigned long long p =
        ((unsigned long long)__float_as_uint(sqrtf(acc[b])) << 32) | (unsigned)u;
    for (int off = 32; off > 0; off >>= 1) {
      unsigned long long q = __shfl_xor(p, off, 64);
      p = q < p ? q : p;
    }
    if (lane == 0) part[(bg * BG + b) * PARTS + us * 4 + wave] = p;
  }
}

// Kernel B: finish argmin per b (all 16 blocks redo the tiny 64-way reduce —
// 8KB L2-hot, cheaper than another kernel), then Gaussian field + threshold.
// Math/order kept EXACTLY as the reference scan (absmax=0.0 verified R6) —
// do not parallelize the b-loop (reassociation -> threshold-flip risk).
__global__ __launch_bounds__(256) void som_out(
    const unsigned long long* __restrict__ part,
    const float* __restrict__ thr, const float* __restrict__ mem0,
    float* __restrict__ out) {
  __shared__ float bys[B_], bxs[B_];
  const int tid = threadIdx.x;
  if (tid < B_) {
    const unsigned long long* p = part + (size_t)tid * PARTS;
    unsigned long long m = p[0];
#pragma unroll
    for (int i = 1; i < PARTS; ++i) {
      unsigned long long q = p[i];
      m = q < m ? q : m;
    }
    unsigned idx = (unsigned)(m & 0xFFFFFFFFu);
    bys[tid] = (float)(idx >> 6);   // bmu_y = idx // W
    bxs[tid] = (float)(idx & 63);   // bmu_x = idx % W
  }
  __syncthreads();

  const int g  = blockIdx.x * 256 + tid;
  const float fy = (float)(g >> 6), fx = (float)(g & 63);

  // cd = sqrt(dy^2+dx^2); nbh = exp(-(cd*cd)*0.125); mem += 0.5*nbh, b=0..127
  float mem = mem0[g];
  for (int b = 0; b < B_; ++b) {
    float dy = fy - bys[b], dx = fx - bxs[b];
    float cd = sqrtf(dy * dy + dx * dx);
    float nbh = expf(-(cd * cd) * 0.125f);  // RADIUS=2 -> 1/(2*R^2)=0.125
    mem += 0.5f * nbh;
  }
  out[g] = (mem > thr[g]) ? 1.0f : 0.0f;
}

extern "C" void kernel_launch(void* const* d_in, const int* in_sizes, int n_in,
                              void* d_out, int out_size, void* d_ws, size_t ws_size,
                              hipStream_t stream) {
  const float* x    = (const float*)d_in[0];   // [128, 256]
  const float* w    = (const float*)d_in[1];   // [64, 64, 256]
  const float* thr  = (const float*)d_in[2];   // [64, 64]
  const float* mem0 = (const float*)d_in[3];   // [64, 64]
  float* out = (float*)d_out;                  // [64, 64]
  unsigned long long* part = (unsigned long long*)d_ws;  // 128*64*8B = 64 KB

  som_bmu<<<dim3(NBG, USL), 256, 0, stream>>>(x, w, part);
  som_out<<<HW_ / 256, 256, 0, stream>>>(part, thr, mem0, out);
}